// Round 13
// baseline (518.265 us; speedup 1.0000x reference)
//
#include <hip/hip_runtime.h>
#include <hip/hip_bf16.h>

#define NEG_SLOPE 0.2f

using bf16 = __hip_bfloat16;

__device__ __forceinline__ float tof(bf16 v) { return __bfloat162float(v); }
__device__ __forceinline__ float tof(float v) { return v; }
__device__ __forceinline__ void store_val(bf16* p, float v) { *p = __float2bfloat16(v); }
__device__ __forceinline__ void store_val(float* p, float v) { *p = v; }

// load 8 consecutive elems of T as fp32 (16B bf16 / 32B fp32)
template <typename T>
__device__ __forceinline__ void load8(const T* p, float* o) {
    if constexpr (sizeof(T) == 2) {
        uint4 raw = *(const uint4*)p;
        const bf16* h = (const bf16*)&raw;
#pragma unroll
        for (int k = 0; k < 8; ++k) o[k] = tof(h[k]);
    } else {
        float4 r0 = *(const float4*)p;
        float4 r1 = *(const float4*)(p + 4);
        o[0] = r0.x; o[1] = r0.y; o[2] = r0.z; o[3] = r0.w;
        o[4] = r1.x; o[5] = r1.y; o[6] = r1.z; o[7] = r1.w;
    }
}

// load 4 consecutive fp32 (16B)
__device__ __forceinline__ void load4f(const float* p, float* o) {
    float4 r = *(const float4*)p;
    o[0] = r.x; o[1] = r.y; o[2] = r.z; o[3] = r.w;
}

// Parallel dtype detect via ballot (validated r6-r12).
__device__ __forceinline__ int detect_ballot(const void* x0, int tid, int* flag4) {
    bool bad = false;
    if (tid < 128) {
        unsigned short u = ((const unsigned short*)x0)[tid];
        float v = __uint_as_float(((unsigned int)u) << 16);
        bad = !(fabsf(v) < 100.f);   // catches NaN too
    }
    unsigned long long m = __ballot(bad);
    if ((tid & 63) == 0) flag4[tid >> 6] = (m != 0ULL);
    __syncthreads();
    return flag4[0] | flag4[1] | flag4[2] | flag4[3];
}

// ===================== Kernel 1: level-0 attn+agg, G=4 batches/block ========
// r12-proven v8 structure scaled to 4 batches per block (same node):
//  - dot phase: the 4 head a-slices are loaded ONCE per j-step and dotted
//    against all 4 batches' x-slices (a-stream amortized 4x);
//  - softmax: 2 passes x 256 threads = 512 items (4 batches x 32 x 4 heads);
//  - aggregate: v6's proven per-batch scalar pattern, looped over 4 batches.
template <typename T, int NS>
__device__ __forceinline__ void agg0v9_core(
    const T* const* selfp, const T* const* neighp,
    const T* a_s, const T* a_n,
    float* const* dstp, float* part2, float* attnT, int tid)
{
    const int u = tid >> 3, c = tid & 7;
    if (u < NS || u == 31) {
        const bool sl = (u == 31);
        const T* src[4];
#pragma unroll
        for (int g = 0; g < 4; ++g)
            src[g] = (sl || u == 0) ? selfp[g] : (neighp[g] + (size_t)(u - 1) * 256);
        const T* a = sl ? a_s : a_n;
        float acc[4][4];
#pragma unroll
        for (int g = 0; g < 4; ++g)
#pragma unroll
            for (int h = 0; h < 4; ++h) acc[g][h] = 0.f;
        if constexpr (sizeof(T) == 2) {
#pragma unroll
            for (int j = 0; j < 4; ++j) {
                const int f = j * 64 + c * 8;
                float av0[8], av1[8], av2[8], av3[8];
                load8(a + 0 * 256 + f, av0);
                load8(a + 1 * 256 + f, av1);
                load8(a + 2 * 256 + f, av2);
                load8(a + 3 * 256 + f, av3);
#pragma unroll
                for (int g = 0; g < 4; ++g) {
                    float xv[8];
                    load8(src[g] + f, xv);
#pragma unroll
                    for (int k = 0; k < 8; ++k) {
                        acc[g][0] += xv[k] * av0[k]; acc[g][1] += xv[k] * av1[k];
                        acc[g][2] += xv[k] * av2[k]; acc[g][3] += xv[k] * av3[k];
                    }
                }
            }
        } else {
#pragma unroll
            for (int j = 0; j < 8; ++j) {
                const int f = j * 32 + c * 4;
                float av0[4], av1[4], av2[4], av3[4];
                load4f((const float*)a + 0 * 256 + f, av0);
                load4f((const float*)a + 1 * 256 + f, av1);
                load4f((const float*)a + 2 * 256 + f, av2);
                load4f((const float*)a + 3 * 256 + f, av3);
#pragma unroll
                for (int g = 0; g < 4; ++g) {
                    float xv[4];
                    load4f((const float*)src[g] + f, xv);
#pragma unroll
                    for (int k = 0; k < 4; ++k) {
                        acc[g][0] += xv[k] * av0[k]; acc[g][1] += xv[k] * av1[k];
                        acc[g][2] += xv[k] * av2[k]; acc[g][3] += xv[k] * av3[k];
                    }
                }
            }
        }
#pragma unroll
        for (int g = 0; g < 4; ++g)
            *(float4*)&part2[g * 1152 + u * 36 + c * 4] =
                make_float4(acc[g][0], acc[g][1], acc[g][2], acc[g][3]);
    }
    __syncthreads();
    // softmax: 2 passes x (2 batches x 32 samples x 4 heads), 32-lane shfl
#pragma unroll
    for (int gg = 0; gg < 2; ++gg) {
        const int g = gg * 2 + (tid >> 7), su = tid & 31, h = (tid >> 5) & 3;
        float v = 0.f;
        if (su < NS || su == 31) {
#pragma unroll
            for (int cc = 0; cc < 8; ++cc)
                v += part2[g * 1152 + su * 36 + cc * 4 + h];
        }
        float ls = __shfl(v, 31, 32);   // self logit lives in lane 31
        float x = -1e30f;
        if (su < NS) { float t = ls + v; x = (t > 0.f) ? t : NEG_SLOPE * t; }
        float m = x;
#pragma unroll
        for (int off = 16; off; off >>= 1) m = fmaxf(m, __shfl_xor(m, off, 32));
        float e = (su < NS) ? __expf(x - m) : 0.f;
        float s = e;
#pragma unroll
        for (int off = 16; off; off >>= 1) s += __shfl_xor(s, off, 32);
        if (su < NS) attnT[g * 128 + su * 4 + h] = e / s;
    }
    __syncthreads();
    // aggregate: v6's proven pattern, once per batch (thread = feature column)
#pragma unroll
    for (int g = 0; g < 4; ++g) {
        const T* selfg  = selfp[g];
        const T* neighg = neighp[g];
        float* dstg     = dstp[g];
        float a0 = 0.f, a1 = 0.f, a2 = 0.f, a3 = 0.f;
#pragma unroll
        for (int s = 0; s < NS; ++s) {
            float4 w = *(const float4*)&attnT[g * 128 + s * 4];  // broadcast
            float xv = tof((s == 0) ? selfg[tid]
                                    : neighg[(size_t)(s - 1) * 256 + tid]);
            a0 += w.x * xv; a1 += w.y * xv; a2 += w.z * xv; a3 += w.w * xv;
        }
        dstg[tid] = a0; dstg[256 + tid] = a1;
        dstg[512 + tid] = a2; dstg[768 + tid] = a3;
    }
}

template <typename T>
__device__ __forceinline__ void agg0v9_launch(
    const T* X0, const T* X1, const T* X2, const T* As, const T* An,
    float* xbar0, float* part2, float* attnT, int b0, int node, int tid)
{
    const T* selfp[4];
    const T* neighp[4];
    float* dstp[4];
    if (node == 0) {
#pragma unroll
        for (int g = 0; g < 4; ++g) {
            selfp[g]  = X0 + (size_t)(b0 + g) * 256;
            neighp[g] = X1 + (size_t)(b0 + g) * 2560;
            dstp[g]   = xbar0 + ((size_t)(b0 + g) * 11 + node) * 1024;
        }
        agg0v9_core<T, 11>(selfp, neighp, As, An, dstp, part2, attnT, tid);
    } else {
        int p = node - 1;
#pragma unroll
        for (int g = 0; g < 4; ++g) {
            selfp[g]  = X1 + ((size_t)(b0 + g) * 10 + p) * 256;
            neighp[g] = X2 + ((size_t)(b0 + g) * 250 + (size_t)p * 25) * 256;
            dstp[g]   = xbar0 + ((size_t)(b0 + g) * 11 + node) * 1024;
        }
        agg0v9_core<T, 26>(selfp, neighp, As, An, dstp, part2, attnT, tid);
    }
}

__global__ __launch_bounds__(256) void gat_agg0v9(
    const void* x0, const void* x1, const void* x2,
    const void* a0s, const void* a0n, float* xbar0)
{
    const int node = blockIdx.x % 11;
    const int b0 = (blockIdx.x / 11) * 4;
    const int tid = threadIdx.x;
    __shared__ __align__(16) float part2[4 * 1152];   // 18432 B
    __shared__ __align__(16) float attnT[512];        // 2048 B
    __shared__ int flag4[4];
    if (detect_ballot(x0, tid, flag4))
        agg0v9_launch<float>((const float*)x0, (const float*)x1, (const float*)x2,
                             (const float*)a0s, (const float*)a0n,
                             xbar0, part2, attnT, b0, node, tid);
    else
        agg0v9_launch<bf16>((const bf16*)x0, (const bf16*)x1, (const bf16*)x2,
                            (const bf16*)a0s, (const bf16*)a0n,
                            xbar0, part2, attnT, b0, node, tid);
}

// ---- wave-parallel logits + softmax on fp32 LDS (validated; root3/fallback)
template <typename T, int F, int NS, int FP>
__device__ __forceinline__ void attention2(const float* xs, const T* a_self,
                                           const T* a_neigh, float (*attnT)[4],
                                           float* part, int tid) {
    const int half = tid >> 7;
    const int grp  = (tid >> 5) & 3;
    const int u    = tid & 31;
    float val = 0.f;
    if (u <= NS) {
        const T* a = ((u < NS) ? a_neigh : a_self) + (size_t)grp * F;
        const float* xrow = xs + (size_t)(u < NS ? u : 0) * FP;
        const int f0 = half * (F / 2);
        float s0 = 0.f, s1 = 0.f, s2 = 0.f, s3 = 0.f;
        float s4 = 0.f, s5 = 0.f, s6 = 0.f, s7 = 0.f;
#pragma unroll 2
        for (int f = f0; f < f0 + F / 2; f += 8) {
            float av[8];
            load8(a + f, av);
            float4 x0 = *(const float4*)(xrow + f);
            float4 x1 = *(const float4*)(xrow + f + 4);
            s0 += x0.x * av[0]; s1 += x0.y * av[1];
            s2 += x0.z * av[2]; s3 += x0.w * av[3];
            s4 += x1.x * av[4]; s5 += x1.y * av[5];
            s6 += x1.z * av[6]; s7 += x1.w * av[7];
        }
        val = ((s0 + s1) + (s2 + s3)) + ((s4 + s5) + (s6 + s7));
    }
    part[tid] = val;
    __syncthreads();
    if (half == 0) {
        float v = part[tid] + part[tid + 128];
        float ls = __shfl(v, NS, 32);
        float x = -1e30f;
        if (u < NS) {
            float t = ls + v;
            x = (t > 0.f) ? t : NEG_SLOPE * t;
        }
        float m = x;
#pragma unroll
        for (int off = 16; off; off >>= 1) m = fmaxf(m, __shfl_xor(m, off, 32));
        float e = (u < NS) ? __expf(x - m) : 0.f;
        float s = e;
#pragma unroll
        for (int off = 16; off; off >>= 1) s += __shfl_xor(s, off, 32);
        if (u < NS) attnT[u][grp] = e / s;
    }
    __syncthreads();
}

// ===================== Kernel 2: level-0 transform GEMM (r3/r7-proven) ======
template <typename T>
__device__ __forceinline__ void gemm0_body(
    const float* __restrict__ X, const T* __restrict__ W, float* __restrict__ Y,
    float* xbt, float* wt, int bid, int tid)
{
    constexpr int MT = 64, KC = 32, MR = 4;
    const int ht = bid % 4;
    const int mt = bid / 4;
    const int n0 = mt * MT;
    const int tx = tid & 15;
    const int ty = tid >> 4;

    const float* Xb = X + (size_t)n0 * 1024 + (size_t)ht * 256;
    const T* Wb = W + (size_t)ht * 256 * 128;

    float acc[MR][8];
#pragma unroll
    for (int m = 0; m < MR; ++m)
#pragma unroll
        for (int d = 0; d < 8; ++d) acc[m][d] = 0.f;

    for (int kc = 0; kc < 256; kc += KC) {
        __syncthreads();
        for (int i = tid; i < MT * KC / 4; i += 256) {
            int r = i >> 3;
            int c = (i & 7) << 2;
            *(float4*)&xbt[r * 36 + c] = *(const float4*)(Xb + (size_t)r * 1024 + kc + c);
        }
        for (int i = tid; i < KC * 16; i += 256) {
            int r = i >> 4, c = (i & 15) << 3;
            float tmp[8];
            load8(Wb + (size_t)(kc + r) * 128 + c, tmp);
            *(float4*)&wt[r * 132 + c] = make_float4(tmp[0], tmp[1], tmp[2], tmp[3]);
            *(float4*)&wt[r * 132 + c + 4] = make_float4(tmp[4], tmp[5], tmp[6], tmp[7]);
        }
        __syncthreads();
#pragma unroll 2
        for (int k = 0; k < KC; k += 4) {
            float4 xv[MR];
#pragma unroll
            for (int m = 0; m < MR; ++m)
                xv[m] = *(const float4*)&xbt[(ty * MR + m) * 36 + k];
#pragma unroll
            for (int kk = 0; kk < 4; ++kk) {
                float wv[8];
                *(float4*)&wv[0] = *(const float4*)&wt[(k + kk) * 132 + tx * 8];
                *(float4*)&wv[4] = *(const float4*)&wt[(k + kk) * 132 + tx * 8 + 4];
#pragma unroll
                for (int m = 0; m < MR; ++m) {
                    float xsv = (kk == 0) ? xv[m].x : (kk == 1) ? xv[m].y
                              : (kk == 2) ? xv[m].z : xv[m].w;
#pragma unroll
                    for (int d = 0; d < 8; ++d) acc[m][d] += xsv * wv[d];
                }
            }
        }
    }
#pragma unroll
    for (int m = 0; m < MR; ++m) {
        float* yp = Y + (size_t)(n0 + ty * MR + m) * 512 + ht * 128 + tx * 8;
        *(float4*)(yp + 0) = make_float4(acc[m][0], acc[m][1], acc[m][2], acc[m][3]);
        *(float4*)(yp + 4) = make_float4(acc[m][4], acc[m][5], acc[m][6], acc[m][7]);
    }
}

__global__ __launch_bounds__(256) void gat_gemm0(
    const void* x0, const float* X, const void* W, float* Y)
{
    __shared__ __align__(16) float xbt[64 * 36];
    __shared__ __align__(16) float wt[32 * 132];
    __shared__ int flag4[4];
    const int tid = threadIdx.x;
    if (detect_ballot(x0, tid, flag4))
        gemm0_body<float>(X, (const float*)W, Y, xbt, wt, blockIdx.x, tid);
    else
        gemm0_body<bf16>(X, (const bf16*)W, Y, xbt, wt, blockIdx.x, tid);
}

// ===================== Kernel 3: root layer, G=4 per block (r7-proven) ======
template <typename T>
__device__ __forceinline__ void root3_body(
    const float* hsws, const T* w1, const T* a1s, const T* a1n, const T* fcw,
    T* out, float* hs, float* xbarAll, float (*attnT)[4], float* part,
    int b0, int tid)
{
    for (int g = 0; g < 4; ++g) {
        int b = b0 + g;
        for (int i = tid; i < 11 * 128; i += 256) {
            int s = i >> 7, f = (i & 127) << 2;
            *(float4*)&hs[s * 516 + f] =
                *(const float4*)(hsws + ((size_t)b * 11 + s) * 512 + f);
        }
        __syncthreads();
        attention2<T, 512, 11, 516>(hs, a1s, a1n, attnT, part, tid);
        float* xbar = xbarAll + g * 2080;
        {
            float a00=0,a01=0,a10=0,a11=0,a20=0,a21=0,a30=0,a31=0;
#pragma unroll
            for (int s = 0; s < 11; ++s) {
                float4 w = *(const float4*)attnT[s];
                float xv0 = hs[s * 516 + tid], xv1 = hs[s * 516 + tid + 256];
                a00 += w.x * xv0; a01 += w.x * xv1;
                a10 += w.y * xv0; a11 += w.y * xv1;
                a20 += w.z * xv0; a21 += w.z * xv1;
                a30 += w.w * xv0; a31 += w.w * xv1;
            }
            int k0 = tid, k1 = tid + 256;
            int o0 = k0 + (k0 >> 7), o1 = k1 + (k1 >> 7);
            xbar[0 * 520 + o0] = a00; xbar[0 * 520 + o1] = a01;
            xbar[1 * 520 + o0] = a10; xbar[1 * 520 + o1] = a11;
            xbar[2 * 520 + o0] = a20; xbar[2 * 520 + o1] = a21;
            xbar[3 * 520 + o0] = a30; xbar[3 * 520 + o1] = a31;
        }
        __syncthreads();
    }

    {
        const int q = tid & 3, g2 = tid >> 2;
        const int h = g2 >> 4, d0 = (g2 & 15) * 8;
        const T* wp = w1 + (size_t)h * 512 * 128 + d0;
        float acc[4][8];
#pragma unroll
        for (int g = 0; g < 4; ++g)
#pragma unroll
            for (int j = 0; j < 8; ++j) acc[g][j] = 0.f;
#pragma unroll 2
        for (int i = 0; i < 128; ++i) {
            float wv[8];
            load8(wp + (size_t)(q * 128 + i) * 128, wv);
#pragma unroll
            for (int g = 0; g < 4; ++g) {
                float xv = xbarAll[g * 2080 + h * 520 + q * 129 + i];
#pragma unroll
                for (int j = 0; j < 8; ++j) acc[g][j] += xv * wv[j];
            }
        }
        __syncthreads();
        float* red = xbarAll;
#pragma unroll
        for (int g = 0; g < 4; ++g) {
            float* r = &red[(q * 64 + g2) * 33 + g * 8];
            *(float4*)(r + 0) = make_float4(acc[g][0], acc[g][1], acc[g][2], acc[g][3]);
            *(float4*)(r + 4) = make_float4(acc[g][4], acc[g][5], acc[g][6], acc[g][7]);
        }
    }
    __syncthreads();
    {
        const int g = tid & 3, t = tid >> 2;
        float s8[8] = {0,0,0,0,0,0,0,0};
#pragma unroll
        for (int q2 = 0; q2 < 4; ++q2) {
            const float* rr = &xbarAll[(q2 * 64 + t) * 33 + g * 8];
            float4 p0 = *(const float4*)rr, p1 = *(const float4*)(rr + 4);
            s8[0] += p0.x; s8[1] += p0.y; s8[2] += p0.z; s8[3] += p0.w;
            s8[4] += p1.x; s8[5] += p1.y; s8[6] += p1.z; s8[7] += p1.w;
        }
        int f0 = (t >> 4) * 128 + (t & 15) * 8;
        float* hp = &hs[g * 545 + f0 + 4 * (f0 >> 6)];
        *(float4*)(hp + 0) = make_float4(s8[0], s8[1], s8[2], s8[3]);
        *(float4*)(hp + 4) = make_float4(s8[4], s8[5], s8[6], s8[7]);
    }
    __syncthreads();
    {
        const int fq = tid >> 5, jb = tid & 31;
        float acc[4][8];
#pragma unroll
        for (int g = 0; g < 4; ++g)
#pragma unroll
            for (int j = 0; j < 8; ++j) acc[g][j] = 0.f;
#pragma unroll 2
        for (int i = 0; i < 64; ++i) {
            float wv[8];
            load8(fcw + (size_t)(fq * 64 + i) * 256 + jb * 8, wv);
#pragma unroll
            for (int g = 0; g < 4; ++g) {
                float xv = hs[g * 545 + fq * 68 + i];
#pragma unroll
                for (int j = 0; j < 8; ++j) acc[g][j] += xv * wv[j];
            }
        }
        __syncthreads();
        float* red2 = xbarAll;
#pragma unroll
        for (int g = 0; g < 4; ++g) {
            float* r = &red2[(fq * 32 + jb) * 33 + g * 8];
            *(float4*)(r + 0) = make_float4(acc[g][0], acc[g][1], acc[g][2], acc[g][3]);
            *(float4*)(r + 4) = make_float4(acc[g][4], acc[g][5], acc[g][6], acc[g][7]);
        }
    }
    __syncthreads();
    if (tid < 128) {
        const int g = tid >> 5, jb = tid & 31;
        float s8[8] = {0,0,0,0,0,0,0,0};
#pragma unroll
        for (int q2 = 0; q2 < 8; ++q2) {
            const float* rr = &xbarAll[(q2 * 32 + jb) * 33 + g * 8];
            float4 p0 = *(const float4*)rr, p1 = *(const float4*)(rr + 4);
            s8[0] += p0.x; s8[1] += p0.y; s8[2] += p0.z; s8[3] += p0.w;
            s8[4] += p1.x; s8[5] += p1.y; s8[6] += p1.z; s8[7] += p1.w;
        }
        T* op = out + (size_t)(b0 + g) * 256 + jb * 8;
#pragma unroll
        for (int j = 0; j < 8; ++j) store_val(op + j, s8[j]);
    }
}

__global__ __launch_bounds__(256) void gat_root3(
    const void* x0, const float* hsws, const void* w1, const void* a1s,
    const void* a1n, const void* fcw, void* out)
{
    const int b0 = blockIdx.x * 4;
    const int tid = threadIdx.x;
    __shared__ __align__(16) float hs[11 * 516];
    __shared__ __align__(16) float xbarAll[8448];
    __shared__ __align__(16) float attnT[26][4];
    __shared__ float part[256];
    __shared__ int flag4[4];
    if (detect_ballot(x0, tid, flag4))
        root3_body<float>(hsws, (const float*)w1, (const float*)a1s,
                          (const float*)a1n, (const float*)fcw, (float*)out,
                          hs, xbarAll, attnT, part, b0, tid);
    else
        root3_body<bf16>(hsws, (const bf16*)w1, (const bf16*)a1s,
                         (const bf16*)a1n, (const bf16*)fcw, (bf16*)out,
                         hs, xbarAll, attnT, part, b0, tid);
}

// ================= Fallback: fully-fused single kernel (ws-less) ============
template <typename T, int F, int NS, int FP>
__device__ __forceinline__ void stage(float* xs, const T* self, const T* neigh, int tid) {
    constexpr int V = 16 / sizeof(T);
    constexpr int TOT = NS * F / V;
    for (int i = tid; i < TOT; i += 256) {
        int e = i * V;
        int s = e / F, f = e % F;
        const T* src = (s == 0) ? (self + f) : (neigh + (size_t)(s - 1) * F + f);
        uint4 raw = *(const uint4*)src;
        const T* hv = (const T*)&raw;
        float* dst = &xs[s * FP + f];
#pragma unroll
        for (int k = 0; k < V; ++k) dst[k] = tof(hv[k]);
    }
}

template <int F, int NS, int FP>
__device__ __forceinline__ void aggregate2(const float* xs, const float (*attnT)[4],
                                           float* xbar, int tid) {
    constexpr int FCH = F / 256;
    float acc[4][FCH];
#pragma unroll
    for (int h = 0; h < 4; ++h)
#pragma unroll
        for (int c = 0; c < FCH; ++c) acc[h][c] = 0.f;
#pragma unroll
    for (int s = 0; s < NS; ++s) {
        float4 w = *(const float4*)attnT[s];
#pragma unroll
        for (int c = 0; c < FCH; ++c) {
            float xv = xs[(size_t)s * FP + tid + c * 256];
            acc[0][c] += w.x * xv;
            acc[1][c] += w.y * xv;
            acc[2][c] += w.z * xv;
            acc[3][c] += w.w * xv;
        }
    }
#pragma unroll
    for (int c = 0; c < FCH; ++c)
#pragma unroll
        for (int h = 0; h < 4; ++h)
            xbar[h * F + tid + c * 256] = acc[h][c];
}

template <typename T, int F>
__device__ __forceinline__ void transform_o(const float* xbar, const T* w,
                                            float* dst, int tid) {
#pragma unroll
    for (int r = 0; r < 2; ++r) {
        int o = tid + r * 256;
        int h = o >> 7, d = o & 127;
        const T* wp = w + (size_t)h * F * 128 + d;
        const float* xb = xbar + (size_t)h * F;
        float a0 = 0.f, a1 = 0.f, a2 = 0.f, a3 = 0.f;
        for (int f = 0; f < F; f += 4) {
            a0 += xb[f + 0] * tof(wp[(size_t)(f + 0) * 128]);
            a1 += xb[f + 1] * tof(wp[(size_t)(f + 1) * 128]);
            a2 += xb[f + 2] * tof(wp[(size_t)(f + 2) * 128]);
            a3 += xb[f + 3] * tof(wp[(size_t)(f + 3) * 128]);
        }
        dst[o] = (a0 + a1) + (a2 + a3);
    }
}

template <typename T>
__device__ __forceinline__ void gat_body_fb(
    const T* x0, const T* x1, const T* x2, const T* w0, const T* a0s,
    const T* a0n, const T* w1, const T* a1s, const T* a1n, const T* fcw,
    T* out, float* xs, float* hs, float* xbar, float (*attnT)[4],
    float* part, float* hroot, int b, int tid)
{
    for (int p = 0; p < 10; ++p) {
        stage<T, 256, 26, 260>(xs, x1 + ((size_t)b * 10 + p) * 256,
                               x2 + ((size_t)b * 250 + (size_t)p * 25) * 256, tid);
        __syncthreads();
        attention2<T, 256, 26, 260>(xs, a0s, a0n, attnT, part, tid);
        aggregate2<256, 26, 260>(xs, attnT, xbar, tid);
        __syncthreads();
        transform_o<T, 256>(xbar, w0, &hs[(p + 1) * 516], tid);
        __syncthreads();
    }
    stage<T, 256, 11, 260>(xs, x0 + (size_t)b * 256, x1 + (size_t)b * 2560, tid);
    __syncthreads();
    attention2<T, 256, 11, 260>(xs, a0s, a0n, attnT, part, tid);
    aggregate2<256, 11, 260>(xs, attnT, xbar, tid);
    __syncthreads();
    transform_o<T, 256>(xbar, w0, &hs[0], tid);
    __syncthreads();
    attention2<T, 512, 11, 516>(hs, a1s, a1n, attnT, part, tid);
    aggregate2<512, 11, 516>(hs, attnT, xbar, tid);
    __syncthreads();
    transform_o<T, 512>(xbar, w1, hroot, tid);
    __syncthreads();
    const T* fp = fcw + tid;
    float a0 = 0.f, a1 = 0.f, a2 = 0.f, a3 = 0.f;
    for (int f = 0; f < 512; f += 4) {
        a0 += hroot[f + 0] * tof(fp[(size_t)(f + 0) * 256]);
        a1 += hroot[f + 1] * tof(fp[(size_t)(f + 1) * 256]);
        a2 += hroot[f + 2] * tof(fp[(size_t)(f + 2) * 256]);
        a3 += hroot[f + 3] * tof(fp[(size_t)(f + 3) * 256]);
    }
    store_val(&out[(size_t)b * 256 + tid], (a0 + a1) + (a2 + a3));
}

__global__ __launch_bounds__(256) void gat_fused(
    const void* x0, const void* x1, const void* x2, const void* w0,
    const void* a0s, const void* a0n, const void* w1, const void* a1s,
    const void* a1n, const void* fcw, void* out)
{
    const int b = blockIdx.x;
    const int tid = threadIdx.x;
    __shared__ __align__(16) float xs[26 * 260];
    __shared__ __align__(16) float hs[11 * 516];
    __shared__ __align__(16) float xbar[4 * 512];
    __shared__ __align__(16) float attnT[26][4];
    __shared__ float part[256];
    __shared__ __align__(16) float hroot[512];
    __shared__ int flag4[4];
    if (detect_ballot(x0, tid, flag4))
        gat_body_fb<float>((const float*)x0, (const float*)x1, (const float*)x2,
                           (const float*)w0, (const float*)a0s, (const float*)a0n,
                           (const float*)w1, (const float*)a1s, (const float*)a1n,
                           (const float*)fcw, (float*)out,
                           xs, hs, xbar, attnT, part, hroot, b, tid);
    else
        gat_body_fb<bf16>((const bf16*)x0, (const bf16*)x1, (const bf16*)x2,
                          (const bf16*)w0, (const bf16*)a0s, (const bf16*)a0n,
                          (const bf16*)w1, (const bf16*)a1s, (const bf16*)a1n,
                          (const bf16*)fcw, (bf16*)out,
                          xs, hs, xbar, attnT, part, hroot, b, tid);
}

extern "C" void kernel_launch(void* const* d_in, const int* in_sizes, int n_in,
                              void* d_out, int out_size, void* d_ws, size_t ws_size,
                              hipStream_t stream) {
    const int B = in_sizes[0] / 256;  // 1024
    // ws layout (floats): xbar0[B*11*1024] | hsws[B*11*512]  (~69.2 MB @ B=1024)
    const size_t ws_need = (size_t)B * 11 * 1536 * sizeof(float);

    if (d_ws && ws_size >= ws_need && ((B * 11) % 64) == 0 && (B % 4) == 0) {
        float* xbar0 = (float*)d_ws;
        float* hsws  = xbar0 + (size_t)B * 11 * 1024;
        gat_agg0v9<<<(B / 4) * 11, 256, 0, stream>>>(d_in[0], d_in[1], d_in[2],
                                                     d_in[4], d_in[5], xbar0);
        gat_gemm0<<<(B * 11 / 64) * 4, 256, 0, stream>>>(d_in[0], xbar0,
                                                         d_in[3], hsws);
        gat_root3<<<B / 4, 256, 0, stream>>>(d_in[0], hsws, d_in[6], d_in[7],
                                             d_in[8], d_in[9], d_out);
    } else {
        gat_fused<<<B, 256, 0, stream>>>(d_in[0], d_in[1], d_in[2], d_in[3],
                                         d_in[4], d_in[5], d_in[6], d_in[7],
                                         d_in[8], d_in[9], d_out);
    }
}

// Round 14
// 510.229 us; speedup vs baseline: 1.0157x; 1.0157x over previous
//
#include <hip/hip_runtime.h>
#include <hip/hip_bf16.h>

#define NEG_SLOPE 0.2f

using bf16 = __hip_bfloat16;

__device__ __forceinline__ float tof(bf16 v) { return __bfloat162float(v); }
__device__ __forceinline__ float tof(float v) { return v; }
__device__ __forceinline__ void store_val(bf16* p, float v) { *p = __float2bfloat16(v); }
__device__ __forceinline__ void store_val(float* p, float v) { *p = v; }

// load 8 consecutive elems of T as fp32 (16B bf16 / 32B fp32)
template <typename T>
__device__ __forceinline__ void load8(const T* p, float* o) {
    if constexpr (sizeof(T) == 2) {
        uint4 raw = *(const uint4*)p;
        const bf16* h = (const bf16*)&raw;
#pragma unroll
        for (int k = 0; k < 8; ++k) o[k] = tof(h[k]);
    } else {
        float4 r0 = *(const float4*)p;
        float4 r1 = *(const float4*)(p + 4);
        o[0] = r0.x; o[1] = r0.y; o[2] = r0.z; o[3] = r0.w;
        o[4] = r1.x; o[5] = r1.y; o[6] = r1.z; o[7] = r1.w;
    }
}

// load 4 consecutive fp32 (16B)
__device__ __forceinline__ void load4f(const float* p, float* o) {
    float4 r = *(const float4*)p;
    o[0] = r.x; o[1] = r.y; o[2] = r.z; o[3] = r.w;
}

// Parallel dtype detect via ballot (validated r6-r13).
__device__ __forceinline__ int detect_ballot(const void* x0, int tid, int* flag4) {
    bool bad = false;
    if (tid < 128) {
        unsigned short u = ((const unsigned short*)x0)[tid];
        float v = __uint_as_float(((unsigned int)u) << 16);
        bad = !(fabsf(v) < 100.f);   // catches NaN too
    }
    unsigned long long m = __ballot(bad);
    if ((tid & 63) == 0) flag4[tid >> 6] = (m != 0ULL);
    __syncthreads();
    return flag4[0] | flag4[1] | flag4[2] | flag4[3];
}

// ===================== Kernel 1: level-0 attn+agg, G=2 batches/block ========
// r12-proven (512 us session best). v6 structure (LDS-free, coalesced
// register ownership) with two batches per block sharing the node index:
//  - dot phase: thread (u = tid>>3, c = tid&7) loads the 4 head a-slices ONCE
//    and dots them against BOTH batches' x-slices (40% fewer VMEM insts);
//  - softmax: all 256 threads (2 batches x 32 samples x 4 heads);
//  - aggregate: v6's exact per-batch scalar pattern (block reads each row
//    once across its 4 waves; float4 remap was 4x redundant -> rejected r11;
//    G=4 flattened -> rejected r13).
template <typename T, int NS>
__device__ __forceinline__ void agg0v8_core(
    const T* self0, const T* neigh0, const T* self1, const T* neigh1,
    const T* a_s, const T* a_n,
    float* dst0, float* dst1, float* part2, float* attnT, int tid)
{
    const int u = tid >> 3, c = tid & 7;
    if (u < NS || u == 31) {
        const bool sl = (u == 31);
        const T* src0 = (sl || u == 0) ? self0 : (neigh0 + (size_t)(u - 1) * 256);
        const T* src1 = (sl || u == 0) ? self1 : (neigh1 + (size_t)(u - 1) * 256);
        const T* a = sl ? a_s : a_n;
        float acc[2][4] = {{0.f,0.f,0.f,0.f},{0.f,0.f,0.f,0.f}};
        if constexpr (sizeof(T) == 2) {
#pragma unroll
            for (int j = 0; j < 4; ++j) {
                const int f = j * 64 + c * 8;
                float av0[8], av1[8], av2[8], av3[8];
                load8(a + 0 * 256 + f, av0);
                load8(a + 1 * 256 + f, av1);
                load8(a + 2 * 256 + f, av2);
                load8(a + 3 * 256 + f, av3);
                float xv[8];
                load8(src0 + f, xv);
#pragma unroll
                for (int k = 0; k < 8; ++k) {
                    acc[0][0] += xv[k] * av0[k]; acc[0][1] += xv[k] * av1[k];
                    acc[0][2] += xv[k] * av2[k]; acc[0][3] += xv[k] * av3[k];
                }
                load8(src1 + f, xv);
#pragma unroll
                for (int k = 0; k < 8; ++k) {
                    acc[1][0] += xv[k] * av0[k]; acc[1][1] += xv[k] * av1[k];
                    acc[1][2] += xv[k] * av2[k]; acc[1][3] += xv[k] * av3[k];
                }
            }
        } else {
#pragma unroll
            for (int j = 0; j < 8; ++j) {
                const int f = j * 32 + c * 4;
                float av0[4], av1[4], av2[4], av3[4];
                load4f((const float*)a + 0 * 256 + f, av0);
                load4f((const float*)a + 1 * 256 + f, av1);
                load4f((const float*)a + 2 * 256 + f, av2);
                load4f((const float*)a + 3 * 256 + f, av3);
                float xv[4];
                load4f((const float*)src0 + f, xv);
#pragma unroll
                for (int k = 0; k < 4; ++k) {
                    acc[0][0] += xv[k] * av0[k]; acc[0][1] += xv[k] * av1[k];
                    acc[0][2] += xv[k] * av2[k]; acc[0][3] += xv[k] * av3[k];
                }
                load4f((const float*)src1 + f, xv);
#pragma unroll
                for (int k = 0; k < 4; ++k) {
                    acc[1][0] += xv[k] * av0[k]; acc[1][1] += xv[k] * av1[k];
                    acc[1][2] += xv[k] * av2[k]; acc[1][3] += xv[k] * av3[k];
                }
            }
        }
        *(float4*)&part2[0 * 1152 + u * 36 + c * 4] =
            make_float4(acc[0][0], acc[0][1], acc[0][2], acc[0][3]);
        *(float4*)&part2[1 * 1152 + u * 36 + c * 4] =
            make_float4(acc[1][0], acc[1][1], acc[1][2], acc[1][3]);
    }
    __syncthreads();
    // softmax: 256 threads = 2 batches x 32 samples x 4 heads, 32-lane shfl
    {
        const int g = tid >> 7, su = tid & 31, h = (tid >> 5) & 3;
        float v = 0.f;
        if (su < NS || su == 31) {
#pragma unroll
            for (int cc = 0; cc < 8; ++cc)
                v += part2[g * 1152 + su * 36 + cc * 4 + h];
        }
        float ls = __shfl(v, 31, 32);   // self logit lives in lane 31
        float x = -1e30f;
        if (su < NS) { float t = ls + v; x = (t > 0.f) ? t : NEG_SLOPE * t; }
        float m = x;
#pragma unroll
        for (int off = 16; off; off >>= 1) m = fmaxf(m, __shfl_xor(m, off, 32));
        float e = (su < NS) ? __expf(x - m) : 0.f;
        float s = e;
#pragma unroll
        for (int off = 16; off; off >>= 1) s += __shfl_xor(s, off, 32);
        if (su < NS) attnT[g * 128 + su * 4 + h] = e / s;
    }
    __syncthreads();
    // aggregate: v6's exact pattern, once per batch (thread = feature column)
#pragma unroll
    for (int g = 0; g < 2; ++g) {
        const T* selfg  = g ? self1 : self0;
        const T* neighg = g ? neigh1 : neigh0;
        float* dstg     = g ? dst1 : dst0;
        float a0 = 0.f, a1 = 0.f, a2 = 0.f, a3 = 0.f;
#pragma unroll
        for (int s = 0; s < NS; ++s) {
            float4 w = *(const float4*)&attnT[g * 128 + s * 4];  // broadcast
            float xv = tof((s == 0) ? selfg[tid]
                                    : neighg[(size_t)(s - 1) * 256 + tid]);
            a0 += w.x * xv; a1 += w.y * xv; a2 += w.z * xv; a3 += w.w * xv;
        }
        dstg[tid] = a0; dstg[256 + tid] = a1;
        dstg[512 + tid] = a2; dstg[768 + tid] = a3;
    }
}

__global__ __launch_bounds__(256) void gat_agg0v8(
    const void* x0, const void* x1, const void* x2,
    const void* a0s, const void* a0n, float* xbar0)
{
    const int node = blockIdx.x % 11;
    const int b0 = (blockIdx.x / 11) * 2;
    const int tid = threadIdx.x;
    __shared__ __align__(16) float part2[2 * 1152];   // 9216 B
    __shared__ __align__(16) float attnT[256];        // 1024 B
    __shared__ int flag4[4];
    float* dst0 = xbar0 + ((size_t)(b0 + 0) * 11 + node) * 1024;
    float* dst1 = xbar0 + ((size_t)(b0 + 1) * 11 + node) * 1024;
    if (detect_ballot(x0, tid, flag4)) {
        const float *X0 = (const float*)x0, *X1 = (const float*)x1, *X2 = (const float*)x2;
        const float *As = (const float*)a0s, *An = (const float*)a0n;
        if (node == 0)
            agg0v8_core<float, 11>(X0 + (size_t)(b0 + 0) * 256, X1 + (size_t)(b0 + 0) * 2560,
                                   X0 + (size_t)(b0 + 1) * 256, X1 + (size_t)(b0 + 1) * 2560,
                                   As, An, dst0, dst1, part2, attnT, tid);
        else {
            int p = node - 1;
            agg0v8_core<float, 26>(X1 + ((size_t)(b0 + 0) * 10 + p) * 256,
                                   X2 + ((size_t)(b0 + 0) * 250 + (size_t)p * 25) * 256,
                                   X1 + ((size_t)(b0 + 1) * 10 + p) * 256,
                                   X2 + ((size_t)(b0 + 1) * 250 + (size_t)p * 25) * 256,
                                   As, An, dst0, dst1, part2, attnT, tid);
        }
    } else {
        const bf16 *X0 = (const bf16*)x0, *X1 = (const bf16*)x1, *X2 = (const bf16*)x2;
        const bf16 *As = (const bf16*)a0s, *An = (const bf16*)a0n;
        if (node == 0)
            agg0v8_core<bf16, 11>(X0 + (size_t)(b0 + 0) * 256, X1 + (size_t)(b0 + 0) * 2560,
                                  X0 + (size_t)(b0 + 1) * 256, X1 + (size_t)(b0 + 1) * 2560,
                                  As, An, dst0, dst1, part2, attnT, tid);
        else {
            int p = node - 1;
            agg0v8_core<bf16, 26>(X1 + ((size_t)(b0 + 0) * 10 + p) * 256,
                                  X2 + ((size_t)(b0 + 0) * 250 + (size_t)p * 25) * 256,
                                  X1 + ((size_t)(b0 + 1) * 10 + p) * 256,
                                  X2 + ((size_t)(b0 + 1) * 250 + (size_t)p * 25) * 256,
                                  As, An, dst0, dst1, part2, attnT, tid);
        }
    }
}

// ---- wave-parallel logits + softmax on fp32 LDS (validated; root3/fallback)
template <typename T, int F, int NS, int FP>
__device__ __forceinline__ void attention2(const float* xs, const T* a_self,
                                           const T* a_neigh, float (*attnT)[4],
                                           float* part, int tid) {
    const int half = tid >> 7;
    const int grp  = (tid >> 5) & 3;
    const int u    = tid & 31;
    float val = 0.f;
    if (u <= NS) {
        const T* a = ((u < NS) ? a_neigh : a_self) + (size_t)grp * F;
        const float* xrow = xs + (size_t)(u < NS ? u : 0) * FP;
        const int f0 = half * (F / 2);
        float s0 = 0.f, s1 = 0.f, s2 = 0.f, s3 = 0.f;
        float s4 = 0.f, s5 = 0.f, s6 = 0.f, s7 = 0.f;
#pragma unroll 2
        for (int f = f0; f < f0 + F / 2; f += 8) {
            float av[8];
            load8(a + f, av);
            float4 x0 = *(const float4*)(xrow + f);
            float4 x1 = *(const float4*)(xrow + f + 4);
            s0 += x0.x * av[0]; s1 += x0.y * av[1];
            s2 += x0.z * av[2]; s3 += x0.w * av[3];
            s4 += x1.x * av[4]; s5 += x1.y * av[5];
            s6 += x1.z * av[6]; s7 += x1.w * av[7];
        }
        val = ((s0 + s1) + (s2 + s3)) + ((s4 + s5) + (s6 + s7));
    }
    part[tid] = val;
    __syncthreads();
    if (half == 0) {
        float v = part[tid] + part[tid + 128];
        float ls = __shfl(v, NS, 32);
        float x = -1e30f;
        if (u < NS) {
            float t = ls + v;
            x = (t > 0.f) ? t : NEG_SLOPE * t;
        }
        float m = x;
#pragma unroll
        for (int off = 16; off; off >>= 1) m = fmaxf(m, __shfl_xor(m, off, 32));
        float e = (u < NS) ? __expf(x - m) : 0.f;
        float s = e;
#pragma unroll
        for (int off = 16; off; off >>= 1) s += __shfl_xor(s, off, 32);
        if (u < NS) attnT[u][grp] = e / s;
    }
    __syncthreads();
}

// ===================== Kernel 2: level-0 transform GEMM (r3/r7-proven) ======
template <typename T>
__device__ __forceinline__ void gemm0_body(
    const float* __restrict__ X, const T* __restrict__ W, float* __restrict__ Y,
    float* xbt, float* wt, int bid, int tid)
{
    constexpr int MT = 64, KC = 32, MR = 4;
    const int ht = bid % 4;
    const int mt = bid / 4;
    const int n0 = mt * MT;
    const int tx = tid & 15;
    const int ty = tid >> 4;

    const float* Xb = X + (size_t)n0 * 1024 + (size_t)ht * 256;
    const T* Wb = W + (size_t)ht * 256 * 128;

    float acc[MR][8];
#pragma unroll
    for (int m = 0; m < MR; ++m)
#pragma unroll
        for (int d = 0; d < 8; ++d) acc[m][d] = 0.f;

    for (int kc = 0; kc < 256; kc += KC) {
        __syncthreads();
        for (int i = tid; i < MT * KC / 4; i += 256) {
            int r = i >> 3;
            int c = (i & 7) << 2;
            *(float4*)&xbt[r * 36 + c] = *(const float4*)(Xb + (size_t)r * 1024 + kc + c);
        }
        for (int i = tid; i < KC * 16; i += 256) {
            int r = i >> 4, c = (i & 15) << 3;
            float tmp[8];
            load8(Wb + (size_t)(kc + r) * 128 + c, tmp);
            *(float4*)&wt[r * 132 + c] = make_float4(tmp[0], tmp[1], tmp[2], tmp[3]);
            *(float4*)&wt[r * 132 + c + 4] = make_float4(tmp[4], tmp[5], tmp[6], tmp[7]);
        }
        __syncthreads();
#pragma unroll 2
        for (int k = 0; k < KC; k += 4) {
            float4 xv[MR];
#pragma unroll
            for (int m = 0; m < MR; ++m)
                xv[m] = *(const float4*)&xbt[(ty * MR + m) * 36 + k];
#pragma unroll
            for (int kk = 0; kk < 4; ++kk) {
                float wv[8];
                *(float4*)&wv[0] = *(const float4*)&wt[(k + kk) * 132 + tx * 8];
                *(float4*)&wv[4] = *(const float4*)&wt[(k + kk) * 132 + tx * 8 + 4];
#pragma unroll
                for (int m = 0; m < MR; ++m) {
                    float xsv = (kk == 0) ? xv[m].x : (kk == 1) ? xv[m].y
                              : (kk == 2) ? xv[m].z : xv[m].w;
#pragma unroll
                    for (int d = 0; d < 8; ++d) acc[m][d] += xsv * wv[d];
                }
            }
        }
    }
#pragma unroll
    for (int m = 0; m < MR; ++m) {
        float* yp = Y + (size_t)(n0 + ty * MR + m) * 512 + ht * 128 + tx * 8;
        *(float4*)(yp + 0) = make_float4(acc[m][0], acc[m][1], acc[m][2], acc[m][3]);
        *(float4*)(yp + 4) = make_float4(acc[m][4], acc[m][5], acc[m][6], acc[m][7]);
    }
}

__global__ __launch_bounds__(256) void gat_gemm0(
    const void* x0, const float* X, const void* W, float* Y)
{
    __shared__ __align__(16) float xbt[64 * 36];
    __shared__ __align__(16) float wt[32 * 132];
    __shared__ int flag4[4];
    const int tid = threadIdx.x;
    if (detect_ballot(x0, tid, flag4))
        gemm0_body<float>(X, (const float*)W, Y, xbt, wt, blockIdx.x, tid);
    else
        gemm0_body<bf16>(X, (const bf16*)W, Y, xbt, wt, blockIdx.x, tid);
}

// ===================== Kernel 3: root layer, G=4 per block (r7-proven) ======
template <typename T>
__device__ __forceinline__ void root3_body(
    const float* hsws, const T* w1, const T* a1s, const T* a1n, const T* fcw,
    T* out, float* hs, float* xbarAll, float (*attnT)[4], float* part,
    int b0, int tid)
{
    for (int g = 0; g < 4; ++g) {
        int b = b0 + g;
        for (int i = tid; i < 11 * 128; i += 256) {
            int s = i >> 7, f = (i & 127) << 2;
            *(float4*)&hs[s * 516 + f] =
                *(const float4*)(hsws + ((size_t)b * 11 + s) * 512 + f);
        }
        __syncthreads();
        attention2<T, 512, 11, 516>(hs, a1s, a1n, attnT, part, tid);
        float* xbar = xbarAll + g * 2080;
        {
            float a00=0,a01=0,a10=0,a11=0,a20=0,a21=0,a30=0,a31=0;
#pragma unroll
            for (int s = 0; s < 11; ++s) {
                float4 w = *(const float4*)attnT[s];
                float xv0 = hs[s * 516 + tid], xv1 = hs[s * 516 + tid + 256];
                a00 += w.x * xv0; a01 += w.x * xv1;
                a10 += w.y * xv0; a11 += w.y * xv1;
                a20 += w.z * xv0; a21 += w.z * xv1;
                a30 += w.w * xv0; a31 += w.w * xv1;
            }
            int k0 = tid, k1 = tid + 256;
            int o0 = k0 + (k0 >> 7), o1 = k1 + (k1 >> 7);
            xbar[0 * 520 + o0] = a00; xbar[0 * 520 + o1] = a01;
            xbar[1 * 520 + o0] = a10; xbar[1 * 520 + o1] = a11;
            xbar[2 * 520 + o0] = a20; xbar[2 * 520 + o1] = a21;
            xbar[3 * 520 + o0] = a30; xbar[3 * 520 + o1] = a31;
        }
        __syncthreads();
    }

    {
        const int q = tid & 3, g2 = tid >> 2;
        const int h = g2 >> 4, d0 = (g2 & 15) * 8;
        const T* wp = w1 + (size_t)h * 512 * 128 + d0;
        float acc[4][8];
#pragma unroll
        for (int g = 0; g < 4; ++g)
#pragma unroll
            for (int j = 0; j < 8; ++j) acc[g][j] = 0.f;
#pragma unroll 2
        for (int i = 0; i < 128; ++i) {
            float wv[8];
            load8(wp + (size_t)(q * 128 + i) * 128, wv);
#pragma unroll
            for (int g = 0; g < 4; ++g) {
                float xv = xbarAll[g * 2080 + h * 520 + q * 129 + i];
#pragma unroll
                for (int j = 0; j < 8; ++j) acc[g][j] += xv * wv[j];
            }
        }
        __syncthreads();
        float* red = xbarAll;
#pragma unroll
        for (int g = 0; g < 4; ++g) {
            float* r = &red[(q * 64 + g2) * 33 + g * 8];
            *(float4*)(r + 0) = make_float4(acc[g][0], acc[g][1], acc[g][2], acc[g][3]);
            *(float4*)(r + 4) = make_float4(acc[g][4], acc[g][5], acc[g][6], acc[g][7]);
        }
    }
    __syncthreads();
    {
        const int g = tid & 3, t = tid >> 2;
        float s8[8] = {0,0,0,0,0,0,0,0};
#pragma unroll
        for (int q2 = 0; q2 < 4; ++q2) {
            const float* rr = &xbarAll[(q2 * 64 + t) * 33 + g * 8];
            float4 p0 = *(const float4*)rr, p1 = *(const float4*)(rr + 4);
            s8[0] += p0.x; s8[1] += p0.y; s8[2] += p0.z; s8[3] += p0.w;
            s8[4] += p1.x; s8[5] += p1.y; s8[6] += p1.z; s8[7] += p1.w;
        }
        int f0 = (t >> 4) * 128 + (t & 15) * 8;
        float* hp = &hs[g * 545 + f0 + 4 * (f0 >> 6)];
        *(float4*)(hp + 0) = make_float4(s8[0], s8[1], s8[2], s8[3]);
        *(float4*)(hp + 4) = make_float4(s8[4], s8[5], s8[6], s8[7]);
    }
    __syncthreads();
    {
        const int fq = tid >> 5, jb = tid & 31;
        float acc[4][8];
#pragma unroll
        for (int g = 0; g < 4; ++g)
#pragma unroll
            for (int j = 0; j < 8; ++j) acc[g][j] = 0.f;
#pragma unroll 2
        for (int i = 0; i < 64; ++i) {
            float wv[8];
            load8(fcw + (size_t)(fq * 64 + i) * 256 + jb * 8, wv);
#pragma unroll
            for (int g = 0; g < 4; ++g) {
                float xv = hs[g * 545 + fq * 68 + i];
#pragma unroll
                for (int j = 0; j < 8; ++j) acc[g][j] += xv * wv[j];
            }
        }
        __syncthreads();
        float* red2 = xbarAll;
#pragma unroll
        for (int g = 0; g < 4; ++g) {
            float* r = &red2[(fq * 32 + jb) * 33 + g * 8];
            *(float4*)(r + 0) = make_float4(acc[g][0], acc[g][1], acc[g][2], acc[g][3]);
            *(float4*)(r + 4) = make_float4(acc[g][4], acc[g][5], acc[g][6], acc[g][7]);
        }
    }
    __syncthreads();
    if (tid < 128) {
        const int g = tid >> 5, jb = tid & 31;
        float s8[8] = {0,0,0,0,0,0,0,0};
#pragma unroll
        for (int q2 = 0; q2 < 8; ++q2) {
            const float* rr = &xbarAll[(q2 * 32 + jb) * 33 + g * 8];
            float4 p0 = *(const float4*)rr, p1 = *(const float4*)(rr + 4);
            s8[0] += p0.x; s8[1] += p0.y; s8[2] += p0.z; s8[3] += p0.w;
            s8[4] += p1.x; s8[5] += p1.y; s8[6] += p1.z; s8[7] += p1.w;
        }
        T* op = out + (size_t)(b0 + g) * 256 + jb * 8;
#pragma unroll
        for (int j = 0; j < 8; ++j) store_val(op + j, s8[j]);
    }
}

__global__ __launch_bounds__(256) void gat_root3(
    const void* x0, const float* hsws, const void* w1, const void* a1s,
    const void* a1n, const void* fcw, void* out)
{
    const int b0 = blockIdx.x * 4;
    const int tid = threadIdx.x;
    __shared__ __align__(16) float hs[11 * 516];
    __shared__ __align__(16) float xbarAll[8448];
    __shared__ __align__(16) float attnT[26][4];
    __shared__ float part[256];
    __shared__ int flag4[4];
    if (detect_ballot(x0, tid, flag4))
        root3_body<float>(hsws, (const float*)w1, (const float*)a1s,
                          (const float*)a1n, (const float*)fcw, (float*)out,
                          hs, xbarAll, attnT, part, b0, tid);
    else
        root3_body<bf16>(hsws, (const bf16*)w1, (const bf16*)a1s,
                         (const bf16*)a1n, (const bf16*)fcw, (bf16*)out,
                         hs, xbarAll, attnT, part, b0, tid);
}

// ================= Fallback: fully-fused single kernel (ws-less) ============
template <typename T, int F, int NS, int FP>
__device__ __forceinline__ void stage(float* xs, const T* self, const T* neigh, int tid) {
    constexpr int V = 16 / sizeof(T);
    constexpr int TOT = NS * F / V;
    for (int i = tid; i < TOT; i += 256) {
        int e = i * V;
        int s = e / F, f = e % F;
        const T* src = (s == 0) ? (self + f) : (neigh + (size_t)(s - 1) * F + f);
        uint4 raw = *(const uint4*)src;
        const T* hv = (const T*)&raw;
        float* dst = &xs[s * FP + f];
#pragma unroll
        for (int k = 0; k < V; ++k) dst[k] = tof(hv[k]);
    }
}

template <int F, int NS, int FP>
__device__ __forceinline__ void aggregate2(const float* xs, const float (*attnT)[4],
                                           float* xbar, int tid) {
    constexpr int FCH = F / 256;
    float acc[4][FCH];
#pragma unroll
    for (int h = 0; h < 4; ++h)
#pragma unroll
        for (int c = 0; c < FCH; ++c) acc[h][c] = 0.f;
#pragma unroll
    for (int s = 0; s < NS; ++s) {
        float4 w = *(const float4*)attnT[s];
#pragma unroll
        for (int c = 0; c < FCH; ++c) {
            float xv = xs[(size_t)s * FP + tid + c * 256];
            acc[0][c] += w.x * xv;
            acc[1][c] += w.y * xv;
            acc[2][c] += w.z * xv;
            acc[3][c] += w.w * xv;
        }
    }
#pragma unroll
    for (int c = 0; c < FCH; ++c)
#pragma unroll
        for (int h = 0; h < 4; ++h)
            xbar[h * F + tid + c * 256] = acc[h][c];
}

template <typename T, int F>
__device__ __forceinline__ void transform_o(const float* xbar, const T* w,
                                            float* dst, int tid) {
#pragma unroll
    for (int r = 0; r < 2; ++r) {
        int o = tid + r * 256;
        int h = o >> 7, d = o & 127;
        const T* wp = w + (size_t)h * F * 128 + d;
        const float* xb = xbar + (size_t)h * F;
        float a0 = 0.f, a1 = 0.f, a2 = 0.f, a3 = 0.f;
        for (int f = 0; f < F; f += 4) {
            a0 += xb[f + 0] * tof(wp[(size_t)(f + 0) * 128]);
            a1 += xb[f + 1] * tof(wp[(size_t)(f + 1) * 128]);
            a2 += xb[f + 2] * tof(wp[(size_t)(f + 2) * 128]);
            a3 += xb[f + 3] * tof(wp[(size_t)(f + 3) * 128]);
        }
        dst[o] = (a0 + a1) + (a2 + a3);
    }
}

template <typename T>
__device__ __forceinline__ void gat_body_fb(
    const T* x0, const T* x1, const T* x2, const T* w0, const T* a0s,
    const T* a0n, const T* w1, const T* a1s, const T* a1n, const T* fcw,
    T* out, float* xs, float* hs, float* xbar, float (*attnT)[4],
    float* part, float* hroot, int b, int tid)
{
    for (int p = 0; p < 10; ++p) {
        stage<T, 256, 26, 260>(xs, x1 + ((size_t)b * 10 + p) * 256,
                               x2 + ((size_t)b * 250 + (size_t)p * 25) * 256, tid);
        __syncthreads();
        attention2<T, 256, 26, 260>(xs, a0s, a0n, attnT, part, tid);
        aggregate2<256, 26, 260>(xs, attnT, xbar, tid);
        __syncthreads();
        transform_o<T, 256>(xbar, w0, &hs[(p + 1) * 516], tid);
        __syncthreads();
    }
    stage<T, 256, 11, 260>(xs, x0 + (size_t)b * 256, x1 + (size_t)b * 2560, tid);
    __syncthreads();
    attention2<T, 256, 11, 260>(xs, a0s, a0n, attnT, part, tid);
    aggregate2<256, 11, 260>(xs, attnT, xbar, tid);
    __syncthreads();
    transform_o<T, 256>(xbar, w0, &hs[0], tid);
    __syncthreads();
    attention2<T, 512, 11, 516>(hs, a1s, a1n, attnT, part, tid);
    aggregate2<512, 11, 516>(hs, attnT, xbar, tid);
    __syncthreads();
    transform_o<T, 512>(xbar, w1, hroot, tid);
    __syncthreads();
    const T* fp = fcw + tid;
    float a0 = 0.f, a1 = 0.f, a2 = 0.f, a3 = 0.f;
    for (int f = 0; f < 512; f += 4) {
        a0 += hroot[f + 0] * tof(fp[(size_t)(f + 0) * 256]);
        a1 += hroot[f + 1] * tof(fp[(size_t)(f + 1) * 256]);
        a2 += hroot[f + 2] * tof(fp[(size_t)(f + 2) * 256]);
        a3 += hroot[f + 3] * tof(fp[(size_t)(f + 3) * 256]);
    }
    store_val(&out[(size_t)b * 256 + tid], (a0 + a1) + (a2 + a3));
}

__global__ __launch_bounds__(256) void gat_fused(
    const void* x0, const void* x1, const void* x2, const void* w0,
    const void* a0s, const void* a0n, const void* w1, const void* a1s,
    const void* a1n, const void* fcw, void* out)
{
    const int b = blockIdx.x;
    const int tid = threadIdx.x;
    __shared__ __align__(16) float xs[26 * 260];
    __shared__ __align__(16) float hs[11 * 516];
    __shared__ __align__(16) float xbar[4 * 512];
    __shared__ __align__(16) float attnT[26][4];
    __shared__ float part[256];
    __shared__ __align__(16) float hroot[512];
    __shared__ int flag4[4];
    if (detect_ballot(x0, tid, flag4))
        gat_body_fb<float>((const float*)x0, (const float*)x1, (const float*)x2,
                           (const float*)w0, (const float*)a0s, (const float*)a0n,
                           (const float*)w1, (const float*)a1s, (const float*)a1n,
                           (const float*)fcw, (float*)out,
                           xs, hs, xbar, attnT, part, hroot, b, tid);
    else
        gat_body_fb<bf16>((const bf16*)x0, (const bf16*)x1, (const bf16*)x2,
                          (const bf16*)w0, (const bf16*)a0s, (const bf16*)a0n,
                          (const bf16*)w1, (const bf16*)a1s, (const bf16*)a1n,
                          (const bf16*)fcw, (bf16*)out,
                          xs, hs, xbar, attnT, part, hroot, b, tid);
}

extern "C" void kernel_launch(void* const* d_in, const int* in_sizes, int n_in,
                              void* d_out, int out_size, void* d_ws, size_t ws_size,
                              hipStream_t stream) {
    const int B = in_sizes[0] / 256;  // 1024
    // ws layout (floats): xbar0[B*11*1024] | hsws[B*11*512]  (~69.2 MB @ B=1024)
    const size_t ws_need = (size_t)B * 11 * 1536 * sizeof(float);

    if (d_ws && ws_size >= ws_need && ((B * 11) % 64) == 0 && (B % 4) == 0) {
        float* xbar0 = (float*)d_ws;
        float* hsws  = xbar0 + (size_t)B * 11 * 1024;
        gat_agg0v8<<<(B / 2) * 11, 256, 0, stream>>>(d_in[0], d_in[1], d_in[2],
                                                     d_in[4], d_in[5], xbar0);
        gat_gemm0<<<(B * 11 / 64) * 4, 256, 0, stream>>>(d_in[0], xbar0,
                                                         d_in[3], hsws);
        gat_root3<<<B / 4, 256, 0, stream>>>(d_in[0], hsws, d_in[6], d_in[7],
                                             d_in[8], d_in[9], d_out);
    } else {
        gat_fused<<<B, 256, 0, stream>>>(d_in[0], d_in[1], d_in[2], d_in[3],
                                         d_in[4], d_in[5], d_in[6], d_in[7],
                                         d_in[8], d_in[9], d_out);
    }
}